// Round 9
// baseline (143.998 us; speedup 1.0000x reference)
//
#include <hip/hip_runtime.h>
#include <hip/hip_bf16.h>

#define BB 4
#define SS 512
#define DD 1024
#define HH 16
#define KR 64
#define HDIM 64
#define THREE_D 3072
#define M_ROWS 2048
#define SCALE_F 0.125f
#define SCALE_LOG2E 0.1803368801111144f

typedef __attribute__((ext_vector_type(8))) short short8;
typedef __attribute__((ext_vector_type(4))) float floatx4;

union F8 { short8 s; unsigned int u[4]; unsigned short h[8]; };

__device__ inline float bfu(unsigned short h){ union{unsigned int u; float f;} c; c.u = ((unsigned int)h) << 16; return c.f; }
__device__ inline unsigned short f2bf(float f){
    union{float f; unsigned int u;} c; c.f = f;
    unsigned int u = c.u;
    return (unsigned short)((u + 0x7fffu + ((u >> 16) & 1u)) >> 16);   // RNE
}
// packed RNE f32x2 -> bf16x2 in one instruction (bit-identical to f2bf for
// finite inputs; no NaNs on these paths). lo in [15:0], hi in [31:16].
__device__ inline unsigned int cvtpk(float lo, float hi){
    unsigned int d;
    asm("v_cvt_pk_bf16_f32 %0, %1, %2" : "=v"(d) : "v"(lo), "v"(hi));
    return d;
}

#define GLOAD_LDS16(g, l)                                                     \
    __builtin_amdgcn_global_load_lds(                                         \
        (const __attribute__((address_space(1))) unsigned int*)(g),           \
        (__attribute__((address_space(3))) unsigned int*)(l), 16, 0, 0)

// ---------------------------------------------------------------------------
// prep: fused cvtA (x->swizzled bf16) + cvtB(w_qkv) + cvtB(w_out) + mask
// ---------------------------------------------------------------------------
__global__ __launch_bounds__(256) void prep_kernel(
    const float* __restrict__ x, const float* __restrict__ w_qkv,
    const float* __restrict__ w_out, const int* __restrict__ routes,
    unsigned short* __restrict__ xb_sw, unsigned short* __restrict__ wb1_sw,
    unsigned short* __restrict__ wb2_sw, unsigned int* __restrict__ maskg)
{
    const int bx = blockIdx.x;
    const int tid = threadIdx.x;
    if (bx < 1024) {
        int gid = bx * 256 + tid;
        int r  = gid & 127;
        int c  = (gid >> 7) & 3;
        int kt = (gid >> 9) & 31;
        int mt = gid >> 14;
        const float* src = x + ((size_t)(mt * 128 + r)) * 1024 + kt * 32 + c * 8;
        float4 a = *(const float4*)src;
        float4 b = *(const float4*)(src + 4);
        F8 o;
        o.u[0] = cvtpk(a.x, a.y);
        o.u[1] = cvtpk(a.z, a.w);
        o.u[2] = cvtpk(b.x, b.y);
        o.u[3] = cvtpk(b.z, b.w);
        *(uint4*)(xb_sw + (size_t)gid * 8) = *(uint4*)&o;
    } else if (bx < 3072) {
        const float* w;
        unsigned short* out;
        int gid, N;
        if (bx < 2560) { w = w_qkv; out = wb1_sw; N = THREE_D; gid = (bx - 1024) * 256 + tid; }
        else           { w = w_out; out = wb2_sw; N = DD;      gid = (bx - 2560) * 256 + tid; }
        int r  = gid & 127;
        int c  = (gid >> 7) & 3;
        int kt = (gid >> 9) & 31;
        int nt = gid >> 14;
        int n = nt * 128 + r;
        int kbase = kt * 32 + c * 8;
        float v[8];
#pragma unroll
        for (int j = 0; j < 8; ++j)
            v[j] = w[(size_t)(kbase + j) * N + n];
        F8 o;
#pragma unroll
        for (int j = 0; j < 4; ++j)
            o.u[j] = cvtpk(v[2 * j], v[2 * j + 1]);
        *(uint4*)(out + (size_t)gid * 8) = *(uint4*)&o;
    } else {
        int q = (bx - 3072) * 256 + tid;
        unsigned int w[16];
#pragma unroll
        for (int i = 0; i < 16; ++i) w[i] = 0u;
        for (int j = 0; j < KR; ++j) {
            int r = routes[q * KR + j];
            if (r <= q) w[r >> 5] |= 1u << (r & 31);
        }
#pragma unroll
        for (int sw = 0; sw < 16; ++sw) maskg[sw * SS + q] = w[sw];
    }
}

// ---------------------------------------------------------------------------
// GEMM1 (QKV) + FUSED BLEND: 64x128 tile, BK=128, 768 blocks.
// R9: 2 WAVES PER BLOCK (128 threads), each wave owns a 64x64 sub-tile.
// MFMA:ds_read ratio per kh goes 8:6 -> 16:8 (square wave-tile); LDS-read
// pressure per CU per K-step -33%; barrier width halves. Same grid (3
// blocks/CU, balanced), same LDS layout, same fused-blend epilogue formulas.
// ---------------------------------------------------------------------------
__global__ __launch_bounds__(128, 2) void gemm_qkv_fused(
    const unsigned short* __restrict__ Asw,
    const unsigned short* __restrict__ Bsw,
    const float* __restrict__ bias,
    unsigned short* __restrict__ qb,
    unsigned short* __restrict__ K2g,
    unsigned short* __restrict__ Vtg)
{
    __shared__ __align__(16) unsigned short Sh[26624];   // 52 KB
    unsigned short* Blds = Sh + 10240;                   // B: 4 kh x 4096

    const int tid  = threadIdx.x;
    const int lane = tid & 63;
    const int wid  = tid >> 6;      // 0..1
    const int l15  = lane & 15;
    const int quad = lane >> 4;

    const int bid  = blockIdx.x;
    const int xcd  = bid & 7;
    const int loc  = bid >> 3;
    const int mt64 = (xcd & 3) * 8 + (loc & 7);
    const int nt   = (xcd >> 2) * 12 + (loc >> 3);

    const bool isQ = (nt < 8);
    const int m0   = mt64 * 64;
    const int n0   = nt * 128;
    const int wn   = wid * 64;      // wave's 64-col half of the tile
    const int base_m = isQ ? m0 : (m0 - 8);

    int rA = base_m + lane;        rA = rA < 0 ? 0 : (rA > 2047 ? 2047 : rA);
    int rB = base_m + 64 + l15;    rB = rB < 0 ? 0 : (rB > 2047 ? 2047 : rB);
    const int cB = lane >> 4;
    const size_t aOffA = ((size_t)(rA >> 7) * 128) * 1024 + (size_t)(rA & 127) * 8;
    const size_t aOffB = ((size_t)(rB >> 7) * 128) * 1024 + (size_t)(rB & 127) * 8;

    floatx4 acc[5][4];
#pragma unroll
    for (int i = 0; i < 5; ++i)
#pragma unroll
        for (int j = 0; j < 4; ++j) acc[i][j] = (floatx4){0.f, 0.f, 0.f, 0.f};

    for (int kt8 = 0; kt8 < 8; ++kt8) {
#pragma unroll
        for (int kh = 0; kh < 4; ++kh) {
            int kt = kt8 * 4 + kh;
            // A main: this wave stages k-octets {wid, wid+2}
#pragma unroll
            for (int koi = 0; koi < 2; ++koi) {
                int ko = wid + koi * 2;
                const unsigned short* ga = Asw + aOffA + (size_t)(kt * 4 + ko) * 1024;
                GLOAD_LDS16(ga, Sh + kh * 2560 + ko * 512 + lane * 8);
            }
            if (!isQ && wid == 0) {
                const unsigned short* ga2 = Asw + aOffB + (size_t)(kt * 4 + cB) * 1024;
                GLOAD_LDS16(ga2, Sh + kh * 2560 + 2048 + lane * 8);
            }
            // B: this wave stages k-octets {wid, wid+2}, 2 issues each
#pragma unroll
            for (int koi = 0; koi < 2; ++koi) {
                int ko = wid + koi * 2;
                const unsigned short* gb = Bsw + (size_t)(nt * 32 + kt) * 4096 + ko * 1024 + lane * 8;
                GLOAD_LDS16(gb,       Blds + kh * 4096 + ko * 1024 + lane * 8);
                GLOAD_LDS16(gb + 512, Blds + kh * 4096 + ko * 1024 + 512 + lane * 8);
            }
        }
        __syncthreads();

#pragma unroll
        for (int kh = 0; kh < 4; ++kh) {
            F8 af[5], bf[4];
#pragma unroll
            for (int emi = 0; emi < 4; ++emi)
                af[emi] = *(const F8*)(Sh + kh * 2560 + (size_t)(quad * 64 + emi * 16 + l15) * 8);
            if (!isQ)
                af[4] = *(const F8*)(Sh + kh * 2560 + 2048 + (size_t)(quad * 16 + l15) * 8);
#pragma unroll
            for (int ni = 0; ni < 4; ++ni)
                bf[ni] = *(const F8*)(Blds + kh * 4096 + (size_t)(quad * 128 + wn + ni * 16 + l15) * 8);
#pragma unroll
            for (int emi = 0; emi < 5; ++emi) {
                if (emi == 4 && isQ) continue;
#pragma unroll
                for (int ni = 0; ni < 4; ++ni)
                    acc[emi][ni] = __builtin_amdgcn_mfma_f32_16x16x32_bf16(
                        af[emi].s, bf[ni].s, acc[emi][ni], 0, 0, 0);
            }
        }
        __syncthreads();
    }

    if (isQ) {
        // ---------- Q path: original epilogue, rows -> qbuf ----------
#pragma unroll
        for (int mi = 0; mi < 4; ++mi) {
#pragma unroll
            for (int ni = 0; ni < 4; ++ni) {
                int col = wn + ni * 16 + l15;
                float bv = bias[n0 + col];
                int row0 = mi * 16 + quad * 4;
                unsigned int p01 = cvtpk(acc[mi][ni][0] + bv, acc[mi][ni][1] + bv);
                unsigned int p23 = cvtpk(acc[mi][ni][2] + bv, acc[mi][ni][3] + bv);
                Sh[(row0 + 0) * 136 + col] = (unsigned short)p01;
                Sh[(row0 + 1) * 136 + col] = (unsigned short)(p01 >> 16);
                Sh[(row0 + 2) * 136 + col] = (unsigned short)p23;
                Sh[(row0 + 3) * 136 + col] = (unsigned short)(p23 >> 16);
            }
        }
        __syncthreads();
        for (int i = tid; i < 1024; i += 128) {
            int rr = i >> 4, cc = i & 15;
            int grow = m0 + rr, gcol = n0 + cc * 8;
            int b = grow >> 9, s = grow & 511;
            int h = gcol >> 6, hd = gcol & 63;
            uint4 val = *(const uint4*)(Sh + rr * 136 + cc * 8);
            *(uint4*)(qb + (((size_t)(b * HH + h) * SS) + s) * HDIM + hd) = val;
        }
    } else {
        // ---------- K/V path: in-register s-blend then layout write ----------
        const bool firstBlk = ((mt64 & 7) == 0);
        const bool lastBlk  = ((mt64 & 7) == 7);
#pragma unroll
        for (int ni = 0; ni < 4; ++ni) {
            int col = wn + ni * 16 + l15;
            float bv = bias[n0 + col];
#pragma unroll
            for (int emi = 0; emi < 5; ++emi) {
                float c0 = acc[emi][ni][0];
                float c3 = acc[emi][ni][3];
                float lA = __shfl_up(c3, 16);
                float lB = (emi > 0) ? __shfl(acc[emi - 1][ni][3], l15 + 48) : 0.f;
                float left0 = (quad == 0) ? lB : lA;
                float rA_ = __shfl_down(c0, 16);
                float rB_ = (emi < 4) ? __shfl(acc[emi + 1][ni][0], l15) : 0.f;
                float right3 = (quad == 3) ? rB_ : rA_;
                float bl[4];
#pragma unroll
                for (int r = 0; r < 4; ++r) {
                    float c = acc[emi][ni][r];
                    float lv = (r == 0) ? left0 : acc[emi][ni][r - 1];
                    float rv = (r == 3) ? right3 : acc[emi][ni][r + 1];
                    if (firstBlk && emi == 0 && quad == 2 && r == 0) lv = c;
                    if (lastBlk  && emi == 4 && quad == 1 && r == 3) rv = c;
                    bl[r] = 0.75f * c + 0.125f * (lv + rv) + bv;
                }
                unsigned int p01 = cvtpk(bl[0], bl[1]);
                unsigned int p23 = cvtpk(bl[2], bl[3]);
                int t0 = emi * 16 + quad * 4 - 8;
                if (t0 >= 0     && t0 < 64)     Sh[t0 * 136 + col]       = (unsigned short)p01;
                if (t0 + 1 >= 0 && t0 + 1 < 64) Sh[(t0 + 1) * 136 + col] = (unsigned short)(p01 >> 16);
                if (t0 + 2 >= 0 && t0 + 2 < 64) Sh[(t0 + 2) * 136 + col] = (unsigned short)p23;
                if (t0 + 3 >= 0 && t0 + 3 < 64) Sh[(t0 + 3) * 136 + col] = (unsigned short)(p23 >> 16);
            }
        }
        __syncthreads();

        const int b   = m0 >> 9;
        const int qd  = (m0 >> 7) & 3;
        const int s0q = m0 & 127;
        if (nt < 16) {
            for (int i = tid; i < 1024; i += 128) {
                int hl = i >> 9, t = (i >> 3) & 63, cc = i & 7;
                int bh = b * 16 + (nt - 8) * 2 + hl;
                int sl = s0q + t;
                uint4 val = *(const uint4*)(Sh + t * 136 + hl * 64 + cc * 8);
                *(uint4*)(K2g + ((size_t)(bh * 4 + qd)) * 8192 +
                          (size_t)(sl * 8 + (cc ^ (sl & 7))) * 8) = val;
            }
        } else {
            for (int i = tid; i < 1024; i += 128) {
                int hl = i >> 9, d = (i >> 3) & 63, t8 = i & 7;
                int bh = b * 16 + (nt - 16) * 2 + hl;
                int scl = (s0q >> 3) + t8;
                F8 o;
#pragma unroll
                for (int a = 0; a < 8; ++a)
                    o.h[a] = Sh[(t8 * 8 + a) * 136 + hl * 64 + d];
                int chunk = d * 16 + (scl & 8) + ((scl ^ d) & 7);
                *(uint4*)(Vtg + ((size_t)(bh * 4 + qd)) * 8192 + (size_t)chunk * 8) = *(uint4*)&o;
            }
        }
    }
}

// ---------------------------------------------------------------------------
// GEMM2 (out proj): 64x64 tile, BK=128 single-buffered (R1 form).
// ---------------------------------------------------------------------------
__global__ __launch_bounds__(256) void gemm_out(
    const unsigned short* __restrict__ Asw,
    const unsigned short* __restrict__ Bsw,
    const float* __restrict__ bias,
    float* __restrict__ Cout)
{
    __shared__ __align__(16) unsigned short Alds[8192];
    __shared__ __align__(16) unsigned short Blds[8192];

    const int tid  = threadIdx.x;
    const int lane = tid & 63;
    const int wid  = tid >> 6;
    const int l15  = lane & 15;
    const int quad = lane >> 4;

    const int bid  = blockIdx.x;
    const int xcd  = bid & 7;
    const int loc  = bid >> 3;
    const int mt64 = (xcd & 3) * 8 + (loc & 7);
    const int nt64 = (xcd >> 2) * 8 + (loc >> 3);

    const int mt  = mt64 >> 1;
    const int rh  = (mt64 & 1) * 64;
    const int ntB = nt64 >> 1;
    const int rhB = (nt64 & 1) * 64;
    const int wm  = (wid >> 1) * 32;
    const int wn  = (wid & 1) * 32;

    floatx4 acc[2][2];
#pragma unroll
    for (int i = 0; i < 2; ++i)
#pragma unroll
        for (int j = 0; j < 2; ++j) acc[i][j] = (floatx4){0.f, 0.f, 0.f, 0.f};

    for (int kt4 = 0; kt4 < 8; ++kt4) {
#pragma unroll
        for (int kh = 0; kh < 4; ++kh) {
            int kt = kt4 * 4 + kh;
            const unsigned short* ga = Asw + ((size_t)(mt  * 32 + kt) * 4 + wid) * 1024 + (rh  + lane) * 8;
            const unsigned short* gb = Bsw + ((size_t)(ntB * 32 + kt) * 4 + wid) * 1024 + (rhB + lane) * 8;
            GLOAD_LDS16(ga, Alds + kh * 2048 + wid * 512 + lane * 8);
            GLOAD_LDS16(gb, Blds + kh * 2048 + wid * 512 + lane * 8);
        }
        __syncthreads();

#pragma unroll
        for (int kh = 0; kh < 4; ++kh) {
            F8 af[2], bf[2];
#pragma unroll
            for (int mi = 0; mi < 2; ++mi)
                af[mi] = *(const F8*)(Alds + kh * 2048 + (size_t)(quad * 64 + wm + mi * 16 + l15) * 8);
#pragma unroll
            for (int ni = 0; ni < 2; ++ni)
                bf[ni] = *(const F8*)(Blds + kh * 2048 + (size_t)(quad * 64 + wn + ni * 16 + l15) * 8);
#pragma unroll
            for (int mi = 0; mi < 2; ++mi)
#pragma unroll
                for (int ni = 0; ni < 2; ++ni)
                    acc[mi][ni] = __builtin_amdgcn_mfma_f32_16x16x32_bf16(
                        af[mi].s, bf[ni].s, acc[mi][ni], 0, 0, 0);
        }
        __syncthreads();
    }

    const int m0 = mt64 * 64;
    const int n0 = nt64 * 64;
#pragma unroll
    for (int mi = 0; mi < 2; ++mi) {
#pragma unroll
        for (int ni = 0; ni < 2; ++ni) {
            int col = n0 + wn + ni * 16 + l15;
            float bv = bias[col];
#pragma unroll
            for (int r = 0; r < 4; ++r) {
                int row = m0 + wm + mi * 16 + quad * 4 + r;
                Cout[(size_t)row * DD + col] = acc[mi][ni][r] + bv;
            }
        }
    }
}

// ---------------------------------------------------------------------------
// Dense masked flash attention with CAUSAL CHUNK SKIPPING. (R1 staging
// structure — proven best. R9: S^T skip tightened from 64-chunk to 16-tile
// granularity. Tiles with s_min > qmaxw are fully masked (mask=0 for r>q in
// prep), so their P is forced to 0 regardless of accS; skipped tiles are
// zero-initialized (removes UB, saves ~12% of S^T MFMAs). Bit-identical.
// ---------------------------------------------------------------------------
__global__ __launch_bounds__(256) void attn_kernel(
    const unsigned short* __restrict__ qb,
    const unsigned short* __restrict__ K2g,
    const unsigned short* __restrict__ Vtg,
    const unsigned int* __restrict__ maskg,
    unsigned short* __restrict__ attn_sw)
{
    __shared__ __align__(16) unsigned short Ks2[2][8192];  // 32 KB
    __shared__ __align__(16) unsigned short Vs2[2][8192];  // 32 KB
    __shared__ __align__(16) unsigned short Ps[4096];      // 8 KB

    const int bid = blockIdx.x;
    const int xcd = bid & 7;
    const int loc = bid >> 3;
    const int bh  = xcd * 8 + (loc & 7);
    const int qt8 = loc >> 3;
    const int qt  = (qt8 < 4) ? qt8 : 11 - qt8;   // {0,1,2,3,7,6,5,4} pairing
    const int b = bh >> 4, h = bh & 15;
    const int tid  = threadIdx.x;
    const int lane = tid & 63;
    const int wid  = tid >> 6;
    const int l15  = lane & 15;
    const int quad = lane >> 4;

    const int nq    = (qt >> 1) + 1;
    const int qmaxw = qt * 64 + wid * 16 + 15;

    const unsigned short* Kbh = K2g + (size_t)bh * 4 * 8192;
    const unsigned short* Vbh = Vtg + (size_t)bh * 4 * 8192;

    #define STAGE(qd, bufi) do {                                              \
        const unsigned short* kq = Kbh + (size_t)(qd) * 8192 + wid * 2048;    \
        const unsigned short* vq = Vbh + (size_t)(qd) * 8192 + wid * 2048;    \
        unsigned short* kl = Ks2[bufi] + wid * 2048;                          \
        unsigned short* vl = Vs2[bufi] + wid * 2048;                          \
        GLOAD_LDS16(kq + lane * 8,        kl + lane * 8);                     \
        GLOAD_LDS16(kq + 512 + lane * 8,  kl + 512 + lane * 8);               \
        GLOAD_LDS16(kq + 1024 + lane * 8, kl + 1024 + lane * 8);              \
        GLOAD_LDS16(kq + 1536 + lane * 8, kl + 1536 + lane * 8);              \
        GLOAD_LDS16(vq + lane * 8,        vl + lane * 8);                     \
        GLOAD_LDS16(vq + 512 + lane * 8,  vl + 512 + lane * 8);               \
        GLOAD_LDS16(vq + 1024 + lane * 8, vl + 1024 + lane * 8);              \
        GLOAD_LDS16(vq + 1536 + lane * 8, vl + 1536 + lane * 8);              \
    } while (0)

    const int q = qt * 64 + wid * 16 + l15;

    F8 qf[2];
    {
        const unsigned short* qrow = qb + ((size_t)bh * SS + q) * 64;
        qf[0] = *(const F8*)(qrow + quad * 8);
        qf[1] = *(const F8*)(qrow + 32 + quad * 8);
    }

    STAGE(0, 0);
    __syncthreads();

    floatx4 accO[4];
#pragma unroll
    for (int dt = 0; dt < 4; ++dt) accO[dt] = (floatx4){0.f, 0.f, 0.f, 0.f};
    float lsum = 0.f;
    unsigned int* Pw = (unsigned int*)Ps + wid * 512;

    for (int qd = 0; qd < nq; ++qd) {
        if (qd + 1 < nq) STAGE(qd + 1, (qd + 1) & 1);
        const unsigned short* Ksb = Ks2[qd & 1];
        const unsigned short* Vsb = Vs2[qd & 1];
        const int sbase128 = qd * 128;

        floatx4 accS[8];
#pragma unroll
        for (int st = 0; st < 8; ++st) {
            if (sbase128 + st * 16 <= qmaxw) {     // 16-tile-granular causal skip
                int srow = st * 16 + l15;
                const F8 k0 = *(const F8*)(Ksb + (((srow << 3) | ( quad      ^ (srow & 7))) << 3));
                const F8 k1 = *(const F8*)(Ksb + (((srow << 3) | ((4 + quad) ^ (srow & 7))) << 3));
                floatx4 a = (floatx4){0.f, 0.f, 0.f, 0.f};
                a = __builtin_amdgcn_mfma_f32_16x16x32_bf16(k0.s, qf[0].s, a, 0, 0, 0);
                a = __builtin_amdgcn_mfma_f32_16x16x32_bf16(k1.s, qf[1].s, a, 0, 0, 0);
                accS[st] = a;
            } else {
                accS[st] = (floatx4){0.f, 0.f, 0.f, 0.f};  // fully masked tile
            }
        }

#pragma unroll
        for (int ch2 = 0; ch2 < 2; ++ch2) {
            if (sbase128 + ch2 * 64 > qmaxw) continue;
            unsigned int mw0 = maskg[(qd * 4 + ch2 * 2) * SS + q];
            unsigned int mw1 = maskg[(qd * 4 + ch2 * 2 + 1) * SS + q];
#pragma unroll
            for (int t = 0; t < 4; ++t) {
                unsigned int mw = (t & 2) ? mw1 : mw0;
                int sbase = (t & 1) * 16 + quad * 4;
                floatx4 a = accS[ch2 * 4 + t];
                float e0 = ((mw >> (sbase + 0)) & 1u) ? exp2f(a[0] * SCALE_LOG2E) : 0.f;
                float e1 = ((mw >> (sbase + 1)) & 1u) ? exp2f(a[1] * SCALE_LOG2E) : 0.f;
                float e2 = ((mw >> (sbase + 2)) & 1u) ? exp2f(a[2] * SCALE_LOG2E) : 0.f;
                float e3 = ((mw >> (sbase + 3)) & 1u) ? exp2f(a[3] * SCALE_LOG2E) : 0.f;
                lsum += (e0 + e1) + (e2 + e3);
                unsigned int w0 = cvtpk(e0, e1);
                unsigned int w1 = cvtpk(e2, e3);
                int off0 = t * 8 + quad * 2;
                int off1 = off0 + 1;
                Pw[l15 * 32 + ((((off0 >> 2) ^ (l15 & 7)) << 2) | (off0 & 3))] = w0;
                Pw[l15 * 32 + ((((off1 >> 2) ^ (l15 & 7)) << 2) | (off1 & 3))] = w1;
            }
            F8 pa[2];
#pragma unroll
            for (int ks = 0; ks < 2; ++ks) {
                int ci = ks * 4 + quad;
                pa[ks] = *(const F8*)((const unsigned short*)(Pw + l15 * 32) +
                                      ((ci ^ (l15 & 7)) << 3));
            }
#pragma unroll
            for (int dt = 0; dt < 4; ++dt) {
                int d = dt * 16 + l15;
#pragma unroll
                for (int ks = 0; ks < 2; ++ks) {
                    int scl = ch2 * 8 + ks * 4 + quad;
                    int chunk = d * 16 + (scl & 8) + ((scl ^ d) & 7);
                    const F8 bv = *(const F8*)(Vsb + ((size_t)chunk << 3));
                    accO[dt] = __builtin_amdgcn_mfma_f32_16x16x32_bf16(pa[ks].s, bv.s, accO[dt], 0, 0, 0);
                }
            }
        }
        __syncthreads();
    }

    lsum += __shfl_xor(lsum, 16);
    lsum += __shfl_xor(lsum, 32);
    float inv = 1.0f / lsum;

    unsigned short* Ow = Ps + wid * 1024;
#pragma unroll
    for (int r = 0; r < 4; ++r) {
        float invr = __shfl(inv, quad * 4 + r);
        unsigned int p01 = cvtpk(accO[0][r] * invr, accO[1][r] * invr);
        unsigned int p23 = cvtpk(accO[2][r] * invr, accO[3][r] * invr);
        int rowb = (quad * 4 + r) * 64;
        Ow[rowb +  0 + l15] = (unsigned short)p01;
        Ow[rowb + 16 + l15] = (unsigned short)(p01 >> 16);
        Ow[rowb + 32 + l15] = (unsigned short)p23;
        Ow[rowb + 48 + l15] = (unsigned short)(p23 >> 16);
    }
#pragma unroll
    for (int i = 0; i < 2; ++i) {
        int ch = i * 64 + lane;
        int qlocal = ch >> 3, j = ch & 7;
        int qq = qt * 64 + wid * 16 + qlocal;
        int mrow = b * SS + qq;
        int mt = mrow >> 7, rr = mrow & 127;
        int kt2 = h * 2 + (j >> 2), c = j & 3;
        size_t gid = (((size_t)(mt * 32 + kt2) * 4 + c) * 128 + rr);
        *(uint4*)(attn_sw + gid * 8) = *(const uint4*)(Ow + qlocal * 64 + j * 8);
    }
    #undef STAGE
}

// ---------------------------------------------------------------------------
extern "C" void kernel_launch(void* const* d_in, const int* in_sizes, int n_in,
                              void* d_out, int out_size, void* d_ws, size_t ws_size,
                              hipStream_t stream)
{
    const float* x     = (const float*)d_in[0];
    const float* w_qkv = (const float*)d_in[1];
    const float* b_qkv = (const float*)d_in[2];
    const float* w_out = (const float*)d_in[3];
    const float* b_out = (const float*)d_in[4];
    const int* routes  = (const int*)d_in[5];

    char* w = (char*)d_ws;
    unsigned short* xb_sw  = (unsigned short*)(w);                 // 4 MB
    unsigned short* wb1_sw = (unsigned short*)(w + (4u  << 20));   // 6 MB
    unsigned short* wb2_sw = (unsigned short*)(w + (10u << 20));   // 2 MB
    unsigned short* qbuf   = (unsigned short*)(w + (12u << 20));   // 4 MB
    unsigned short* K2g    = (unsigned short*)(w + (24u << 20));   // 4 MB
    unsigned short* Vtg    = (unsigned short*)(w + (28u << 20));   // 4 MB
    unsigned short* attnsw = (unsigned short*)(w + (32u << 20));   // 4 MB
    unsigned int*   maskg  = (unsigned int*)(w + (36u << 20));     // 32 KB

    prep_kernel<<<3074, 256, 0, stream>>>(x, w_qkv, w_out, routes,
                                          xb_sw, wb1_sw, wb2_sw, maskg);

    gemm_qkv_fused<<<768, 128, 0, stream>>>(xb_sw, wb1_sw, b_qkv,
                                            qbuf, K2g, Vtg);

    attn_kernel<<<512, 256, 0, stream>>>(qbuf, K2g, Vtg, maskg, attnsw);

    gemm_out<<<512, 256, 0, stream>>>(attnsw, wb2_sw, b_out, (float*)d_out);
}

// Round 10
// 141.937 us; speedup vs baseline: 1.0145x; 1.0145x over previous
//
#include <hip/hip_runtime.h>
#include <hip/hip_bf16.h>

#define BB 4
#define SS 512
#define DD 1024
#define HH 16
#define KR 64
#define HDIM 64
#define THREE_D 3072
#define M_ROWS 2048
#define SCALE_F 0.125f
#define SCALE_LOG2E 0.1803368801111144f

typedef __attribute__((ext_vector_type(8))) short short8;
typedef __attribute__((ext_vector_type(4))) float floatx4;

union F8 { short8 s; unsigned int u[4]; unsigned short h[8]; };

__device__ inline float bfu(unsigned short h){ union{unsigned int u; float f;} c; c.u = ((unsigned int)h) << 16; return c.f; }
__device__ inline unsigned short f2bf(float f){
    union{float f; unsigned int u;} c; c.f = f;
    unsigned int u = c.u;
    return (unsigned short)((u + 0x7fffu + ((u >> 16) & 1u)) >> 16);   // RNE
}
// packed RNE f32x2 -> bf16x2 in one instruction (bit-identical to f2bf for
// finite inputs; no NaNs on these paths). lo in [15:0], hi in [31:16].
__device__ inline unsigned int cvtpk(float lo, float hi){
    unsigned int d;
    asm("v_cvt_pk_bf16_f32 %0, %1, %2" : "=v"(d) : "v"(lo), "v"(hi));
    return d;
}

#define GLOAD_LDS16(g, l)                                                     \
    __builtin_amdgcn_global_load_lds(                                         \
        (const __attribute__((address_space(1))) unsigned int*)(g),           \
        (__attribute__((address_space(3))) unsigned int*)(l), 16, 0, 0)

// ---------------------------------------------------------------------------
// prep: fused cvtA (x->swizzled bf16) + cvtB(w_qkv) + cvtB(w_out) + mask
// ---------------------------------------------------------------------------
__global__ __launch_bounds__(256) void prep_kernel(
    const float* __restrict__ x, const float* __restrict__ w_qkv,
    const float* __restrict__ w_out, const int* __restrict__ routes,
    unsigned short* __restrict__ xb_sw, unsigned short* __restrict__ wb1_sw,
    unsigned short* __restrict__ wb2_sw, unsigned int* __restrict__ maskg)
{
    const int bx = blockIdx.x;
    const int tid = threadIdx.x;
    if (bx < 1024) {
        int gid = bx * 256 + tid;
        int r  = gid & 127;
        int c  = (gid >> 7) & 3;
        int kt = (gid >> 9) & 31;
        int mt = gid >> 14;
        const float* src = x + ((size_t)(mt * 128 + r)) * 1024 + kt * 32 + c * 8;
        float4 a = *(const float4*)src;
        float4 b = *(const float4*)(src + 4);
        F8 o;
        o.u[0] = cvtpk(a.x, a.y);
        o.u[1] = cvtpk(a.z, a.w);
        o.u[2] = cvtpk(b.x, b.y);
        o.u[3] = cvtpk(b.z, b.w);
        *(uint4*)(xb_sw + (size_t)gid * 8) = *(uint4*)&o;
    } else if (bx < 3072) {
        const float* w;
        unsigned short* out;
        int gid, N;
        if (bx < 2560) { w = w_qkv; out = wb1_sw; N = THREE_D; gid = (bx - 1024) * 256 + tid; }
        else           { w = w_out; out = wb2_sw; N = DD;      gid = (bx - 2560) * 256 + tid; }
        int r  = gid & 127;
        int c  = (gid >> 7) & 3;
        int kt = (gid >> 9) & 31;
        int nt = gid >> 14;
        int n = nt * 128 + r;
        int kbase = kt * 32 + c * 8;
        float v[8];
#pragma unroll
        for (int j = 0; j < 8; ++j)
            v[j] = w[(size_t)(kbase + j) * N + n];
        F8 o;
#pragma unroll
        for (int j = 0; j < 4; ++j)
            o.u[j] = cvtpk(v[2 * j], v[2 * j + 1]);
        *(uint4*)(out + (size_t)gid * 8) = *(uint4*)&o;
    } else {
        int q = (bx - 3072) * 256 + tid;
        unsigned int w[16];
#pragma unroll
        for (int i = 0; i < 16; ++i) w[i] = 0u;
        for (int j = 0; j < KR; ++j) {
            int r = routes[q * KR + j];
            if (r <= q) w[r >> 5] |= 1u << (r & 31);
        }
#pragma unroll
        for (int sw = 0; sw < 16; ++sw) maskg[sw * SS + q] = w[sw];
    }
}

// ---------------------------------------------------------------------------
// GEMM1 (QKV) + FUSED BLEND: 64x128 tile, BK=128, 768 blocks, 256 threads.
// (R8 form exact — proven best at 138.0us. R9's 2-wave variant regressed
// +6us: 6 waves/CU vs 12 exposed staging latency; occupancy > instr mix.)
// ---------------------------------------------------------------------------
__global__ __launch_bounds__(256, 3) void gemm_qkv_fused(
    const unsigned short* __restrict__ Asw,
    const unsigned short* __restrict__ Bsw,
    const float* __restrict__ bias,
    unsigned short* __restrict__ qb,
    unsigned short* __restrict__ K2g,
    unsigned short* __restrict__ Vtg)
{
    __shared__ __align__(16) unsigned short Sh[26624];   // 52 KB
    unsigned short* Blds = Sh + 10240;                   // B: 4 kh x 4096

    const int tid  = threadIdx.x;
    const int lane = tid & 63;
    const int wid  = tid >> 6;
    const int l15  = lane & 15;
    const int quad = lane >> 4;

    const int bid  = blockIdx.x;
    const int xcd  = bid & 7;
    const int loc  = bid >> 3;
    const int mt64 = (xcd & 3) * 8 + (loc & 7);
    const int nt   = (xcd >> 2) * 12 + (loc >> 3);

    const bool isQ = (nt < 8);
    const int m0   = mt64 * 64;
    const int n0   = nt * 128;
    const int wn   = wid * 32;
    const int base_m = isQ ? m0 : (m0 - 8);

    int rA = base_m + lane;        rA = rA < 0 ? 0 : (rA > 2047 ? 2047 : rA);
    int rB = base_m + 64 + l15;    rB = rB < 0 ? 0 : (rB > 2047 ? 2047 : rB);
    const int cB = lane >> 4;
    const size_t aOffA = ((size_t)(rA >> 7) * 128) * 1024 + (size_t)(rA & 127) * 8;
    const size_t aOffB = ((size_t)(rB >> 7) * 128) * 1024 + (size_t)(rB & 127) * 8;

    floatx4 acc[5][2];
#pragma unroll
    for (int i = 0; i < 5; ++i)
#pragma unroll
        for (int j = 0; j < 2; ++j) acc[i][j] = (floatx4){0.f, 0.f, 0.f, 0.f};

    for (int kt8 = 0; kt8 < 8; ++kt8) {
#pragma unroll
        for (int kh = 0; kh < 4; ++kh) {
            int kt = kt8 * 4 + kh;
            const unsigned short* ga = Asw + aOffA + (size_t)(kt * 4 + wid) * 1024;
            GLOAD_LDS16(ga, Sh + kh * 2560 + wid * 512 + lane * 8);
            if (!isQ && wid == 0) {
                const unsigned short* ga2 = Asw + aOffB + (size_t)(kt * 4 + cB) * 1024;
                GLOAD_LDS16(ga2, Sh + kh * 2560 + 2048 + lane * 8);
            }
            const unsigned short* gb = Bsw + (size_t)(nt * 32 + kt) * 4096 + wid * 1024 + lane * 8;
            GLOAD_LDS16(gb,       Blds + kh * 4096 + wid * 1024 + lane * 8);
            GLOAD_LDS16(gb + 512, Blds + kh * 4096 + wid * 1024 + 512 + lane * 8);
        }
        __syncthreads();

#pragma unroll
        for (int kh = 0; kh < 4; ++kh) {
            F8 af[5], bf[2];
#pragma unroll
            for (int emi = 0; emi < 4; ++emi)
                af[emi] = *(const F8*)(Sh + kh * 2560 + (size_t)(quad * 64 + emi * 16 + l15) * 8);
            if (!isQ)
                af[4] = *(const F8*)(Sh + kh * 2560 + 2048 + (size_t)(quad * 16 + l15) * 8);
#pragma unroll
            for (int ni = 0; ni < 2; ++ni)
                bf[ni] = *(const F8*)(Blds + kh * 4096 + (size_t)(quad * 128 + wn + ni * 16 + l15) * 8);
#pragma unroll
            for (int emi = 0; emi < 5; ++emi) {
                if (emi == 4 && isQ) continue;
#pragma unroll
                for (int ni = 0; ni < 2; ++ni)
                    acc[emi][ni] = __builtin_amdgcn_mfma_f32_16x16x32_bf16(
                        af[emi].s, bf[ni].s, acc[emi][ni], 0, 0, 0);
            }
        }
        __syncthreads();
    }

    if (isQ) {
        // ---------- Q path: original epilogue, rows -> qbuf ----------
#pragma unroll
        for (int mi = 0; mi < 4; ++mi) {
#pragma unroll
            for (int ni = 0; ni < 2; ++ni) {
                int col = wn + ni * 16 + l15;
                float bv = bias[n0 + col];
                int row0 = mi * 16 + quad * 4;
                unsigned int p01 = cvtpk(acc[mi][ni][0] + bv, acc[mi][ni][1] + bv);
                unsigned int p23 = cvtpk(acc[mi][ni][2] + bv, acc[mi][ni][3] + bv);
                Sh[(row0 + 0) * 136 + col] = (unsigned short)p01;
                Sh[(row0 + 1) * 136 + col] = (unsigned short)(p01 >> 16);
                Sh[(row0 + 2) * 136 + col] = (unsigned short)p23;
                Sh[(row0 + 3) * 136 + col] = (unsigned short)(p23 >> 16);
            }
        }
        __syncthreads();
        for (int i = tid; i < 1024; i += 256) {
            int rr = i >> 4, cc = i & 15;
            int grow = m0 + rr, gcol = n0 + cc * 8;
            int b = grow >> 9, s = grow & 511;
            int h = gcol >> 6, hd = gcol & 63;
            uint4 val = *(const uint4*)(Sh + rr * 136 + cc * 8);
            *(uint4*)(qb + (((size_t)(b * HH + h) * SS) + s) * HDIM + hd) = val;
        }
    } else {
        // ---------- K/V path: in-register s-blend then layout write ----------
        const bool firstBlk = ((mt64 & 7) == 0);
        const bool lastBlk  = ((mt64 & 7) == 7);
#pragma unroll
        for (int ni = 0; ni < 2; ++ni) {
            int col = wn + ni * 16 + l15;
            float bv = bias[n0 + col];
#pragma unroll
            for (int emi = 0; emi < 5; ++emi) {
                float c0 = acc[emi][ni][0];
                float c3 = acc[emi][ni][3];
                float lA = __shfl_up(c3, 16);
                float lB = (emi > 0) ? __shfl(acc[emi - 1][ni][3], l15 + 48) : 0.f;
                float left0 = (quad == 0) ? lB : lA;
                float rA_ = __shfl_down(c0, 16);
                float rB_ = (emi < 4) ? __shfl(acc[emi + 1][ni][0], l15) : 0.f;
                float right3 = (quad == 3) ? rB_ : rA_;
                float bl[4];
#pragma unroll
                for (int r = 0; r < 4; ++r) {
                    float c = acc[emi][ni][r];
                    float lv = (r == 0) ? left0 : acc[emi][ni][r - 1];
                    float rv = (r == 3) ? right3 : acc[emi][ni][r + 1];
                    if (firstBlk && emi == 0 && quad == 2 && r == 0) lv = c;
                    if (lastBlk  && emi == 4 && quad == 1 && r == 3) rv = c;
                    bl[r] = 0.75f * c + 0.125f * (lv + rv) + bv;
                }
                unsigned int p01 = cvtpk(bl[0], bl[1]);
                unsigned int p23 = cvtpk(bl[2], bl[3]);
                int t0 = emi * 16 + quad * 4 - 8;
                if (t0 >= 0     && t0 < 64)     Sh[t0 * 136 + col]       = (unsigned short)p01;
                if (t0 + 1 >= 0 && t0 + 1 < 64) Sh[(t0 + 1) * 136 + col] = (unsigned short)(p01 >> 16);
                if (t0 + 2 >= 0 && t0 + 2 < 64) Sh[(t0 + 2) * 136 + col] = (unsigned short)p23;
                if (t0 + 3 >= 0 && t0 + 3 < 64) Sh[(t0 + 3) * 136 + col] = (unsigned short)(p23 >> 16);
            }
        }
        __syncthreads();

        const int b   = m0 >> 9;
        const int qd  = (m0 >> 7) & 3;
        const int s0q = m0 & 127;
        if (nt < 16) {
            for (int i = tid; i < 1024; i += 256) {
                int hl = i >> 9, t = (i >> 3) & 63, cc = i & 7;
                int bh = b * 16 + (nt - 8) * 2 + hl;
                int sl = s0q + t;
                uint4 val = *(const uint4*)(Sh + t * 136 + hl * 64 + cc * 8);
                *(uint4*)(K2g + ((size_t)(bh * 4 + qd)) * 8192 +
                          (size_t)(sl * 8 + (cc ^ (sl & 7))) * 8) = val;
            }
        } else {
            for (int i = tid; i < 1024; i += 256) {
                int hl = i >> 9, d = (i >> 3) & 63, t8 = i & 7;
                int bh = b * 16 + (nt - 16) * 2 + hl;
                int scl = (s0q >> 3) + t8;
                F8 o;
#pragma unroll
                for (int a = 0; a < 8; ++a)
                    o.h[a] = Sh[(t8 * 8 + a) * 136 + hl * 64 + d];
                int chunk = d * 16 + (scl & 8) + ((scl ^ d) & 7);
                *(uint4*)(Vtg + ((size_t)(bh * 4 + qd)) * 8192 + (size_t)chunk * 8) = *(uint4*)&o;
            }
        }
    }
}

// ---------------------------------------------------------------------------
// GEMM2 (out proj): 64x64 tile, BK=128 single-buffered (R1 form).
// ---------------------------------------------------------------------------
__global__ __launch_bounds__(256) void gemm_out(
    const unsigned short* __restrict__ Asw,
    const unsigned short* __restrict__ Bsw,
    const float* __restrict__ bias,
    float* __restrict__ Cout)
{
    __shared__ __align__(16) unsigned short Alds[8192];
    __shared__ __align__(16) unsigned short Blds[8192];

    const int tid  = threadIdx.x;
    const int lane = tid & 63;
    const int wid  = tid >> 6;
    const int l15  = lane & 15;
    const int quad = lane >> 4;

    const int bid  = blockIdx.x;
    const int xcd  = bid & 7;
    const int loc  = bid >> 3;
    const int mt64 = (xcd & 3) * 8 + (loc & 7);
    const int nt64 = (xcd >> 2) * 8 + (loc >> 3);

    const int mt  = mt64 >> 1;
    const int rh  = (mt64 & 1) * 64;
    const int ntB = nt64 >> 1;
    const int rhB = (nt64 & 1) * 64;
    const int wm  = (wid >> 1) * 32;
    const int wn  = (wid & 1) * 32;

    floatx4 acc[2][2];
#pragma unroll
    for (int i = 0; i < 2; ++i)
#pragma unroll
        for (int j = 0; j < 2; ++j) acc[i][j] = (floatx4){0.f, 0.f, 0.f, 0.f};

    for (int kt4 = 0; kt4 < 8; ++kt4) {
#pragma unroll
        for (int kh = 0; kh < 4; ++kh) {
            int kt = kt4 * 4 + kh;
            const unsigned short* ga = Asw + ((size_t)(mt  * 32 + kt) * 4 + wid) * 1024 + (rh  + lane) * 8;
            const unsigned short* gb = Bsw + ((size_t)(ntB * 32 + kt) * 4 + wid) * 1024 + (rhB + lane) * 8;
            GLOAD_LDS16(ga, Alds + kh * 2048 + wid * 512 + lane * 8);
            GLOAD_LDS16(gb, Blds + kh * 2048 + wid * 512 + lane * 8);
        }
        __syncthreads();

#pragma unroll
        for (int kh = 0; kh < 4; ++kh) {
            F8 af[2], bf[2];
#pragma unroll
            for (int mi = 0; mi < 2; ++mi)
                af[mi] = *(const F8*)(Alds + kh * 2048 + (size_t)(quad * 64 + wm + mi * 16 + l15) * 8);
#pragma unroll
            for (int ni = 0; ni < 2; ++ni)
                bf[ni] = *(const F8*)(Blds + kh * 2048 + (size_t)(quad * 64 + wn + ni * 16 + l15) * 8);
#pragma unroll
            for (int mi = 0; mi < 2; ++mi)
#pragma unroll
                for (int ni = 0; ni < 2; ++ni)
                    acc[mi][ni] = __builtin_amdgcn_mfma_f32_16x16x32_bf16(
                        af[mi].s, bf[ni].s, acc[mi][ni], 0, 0, 0);
        }
        __syncthreads();
    }

    const int m0 = mt64 * 64;
    const int n0 = nt64 * 64;
#pragma unroll
    for (int mi = 0; mi < 2; ++mi) {
#pragma unroll
        for (int ni = 0; ni < 2; ++ni) {
            int col = n0 + wn + ni * 16 + l15;
            float bv = bias[col];
#pragma unroll
            for (int r = 0; r < 4; ++r) {
                int row = m0 + wm + mi * 16 + quad * 4 + r;
                Cout[(size_t)row * DD + col] = acc[mi][ni][r] + bv;
            }
        }
    }
}

// ---------------------------------------------------------------------------
// Dense masked flash attention with CAUSAL CHUNK SKIPPING. (R1 staging
// structure — proven best. Keeps R9's 16-tile-granular S^T skip: tiles with
// s_min > qmaxw are fully masked (mask=0 for r>q in prep) so their P is 0
// regardless of accS; skipped tiles zero-init. Bit-identical, ~12% fewer
// S^T MFMAs.)
// ---------------------------------------------------------------------------
__global__ __launch_bounds__(256) void attn_kernel(
    const unsigned short* __restrict__ qb,
    const unsigned short* __restrict__ K2g,
    const unsigned short* __restrict__ Vtg,
    const unsigned int* __restrict__ maskg,
    unsigned short* __restrict__ attn_sw)
{
    __shared__ __align__(16) unsigned short Ks2[2][8192];  // 32 KB
    __shared__ __align__(16) unsigned short Vs2[2][8192];  // 32 KB
    __shared__ __align__(16) unsigned short Ps[4096];      // 8 KB

    const int bid = blockIdx.x;
    const int xcd = bid & 7;
    const int loc = bid >> 3;
    const int bh  = xcd * 8 + (loc & 7);
    const int qt8 = loc >> 3;
    const int qt  = (qt8 < 4) ? qt8 : 11 - qt8;   // {0,1,2,3,7,6,5,4} pairing
    const int b = bh >> 4, h = bh & 15;
    const int tid  = threadIdx.x;
    const int lane = tid & 63;
    const int wid  = tid >> 6;
    const int l15  = lane & 15;
    const int quad = lane >> 4;

    const int nq    = (qt >> 1) + 1;
    const int qmaxw = qt * 64 + wid * 16 + 15;

    const unsigned short* Kbh = K2g + (size_t)bh * 4 * 8192;
    const unsigned short* Vbh = Vtg + (size_t)bh * 4 * 8192;

    #define STAGE(qd, bufi) do {                                              \
        const unsigned short* kq = Kbh + (size_t)(qd) * 8192 + wid * 2048;    \
        const unsigned short* vq = Vbh + (size_t)(qd) * 8192 + wid * 2048;    \
        unsigned short* kl = Ks2[bufi] + wid * 2048;                          \
        unsigned short* vl = Vs2[bufi] + wid * 2048;                          \
        GLOAD_LDS16(kq + lane * 8,        kl + lane * 8);                     \
        GLOAD_LDS16(kq + 512 + lane * 8,  kl + 512 + lane * 8);               \
        GLOAD_LDS16(kq + 1024 + lane * 8, kl + 1024 + lane * 8);              \
        GLOAD_LDS16(kq + 1536 + lane * 8, kl + 1536 + lane * 8);              \
        GLOAD_LDS16(vq + lane * 8,        vl + lane * 8);                     \
        GLOAD_LDS16(vq + 512 + lane * 8,  vl + 512 + lane * 8);               \
        GLOAD_LDS16(vq + 1024 + lane * 8, vl + 1024 + lane * 8);              \
        GLOAD_LDS16(vq + 1536 + lane * 8, vl + 1536 + lane * 8);              \
    } while (0)

    const int q = qt * 64 + wid * 16 + l15;

    F8 qf[2];
    {
        const unsigned short* qrow = qb + ((size_t)bh * SS + q) * 64;
        qf[0] = *(const F8*)(qrow + quad * 8);
        qf[1] = *(const F8*)(qrow + 32 + quad * 8);
    }

    STAGE(0, 0);
    __syncthreads();

    floatx4 accO[4];
#pragma unroll
    for (int dt = 0; dt < 4; ++dt) accO[dt] = (floatx4){0.f, 0.f, 0.f, 0.f};
    float lsum = 0.f;
    unsigned int* Pw = (unsigned int*)Ps + wid * 512;

    for (int qd = 0; qd < nq; ++qd) {
        if (qd + 1 < nq) STAGE(qd + 1, (qd + 1) & 1);
        const unsigned short* Ksb = Ks2[qd & 1];
        const unsigned short* Vsb = Vs2[qd & 1];
        const int sbase128 = qd * 128;

        floatx4 accS[8];
#pragma unroll
        for (int st = 0; st < 8; ++st) {
            if (sbase128 + st * 16 <= qmaxw) {     // 16-tile-granular causal skip
                int srow = st * 16 + l15;
                const F8 k0 = *(const F8*)(Ksb + (((srow << 3) | ( quad      ^ (srow & 7))) << 3));
                const F8 k1 = *(const F8*)(Ksb + (((srow << 3) | ((4 + quad) ^ (srow & 7))) << 3));
                floatx4 a = (floatx4){0.f, 0.f, 0.f, 0.f};
                a = __builtin_amdgcn_mfma_f32_16x16x32_bf16(k0.s, qf[0].s, a, 0, 0, 0);
                a = __builtin_amdgcn_mfma_f32_16x16x32_bf16(k1.s, qf[1].s, a, 0, 0, 0);
                accS[st] = a;
            } else {
                accS[st] = (floatx4){0.f, 0.f, 0.f, 0.f};  // fully masked tile
            }
        }

#pragma unroll
        for (int ch2 = 0; ch2 < 2; ++ch2) {
            if (sbase128 + ch2 * 64 > qmaxw) continue;
            unsigned int mw0 = maskg[(qd * 4 + ch2 * 2) * SS + q];
            unsigned int mw1 = maskg[(qd * 4 + ch2 * 2 + 1) * SS + q];
#pragma unroll
            for (int t = 0; t < 4; ++t) {
                unsigned int mw = (t & 2) ? mw1 : mw0;
                int sbase = (t & 1) * 16 + quad * 4;
                floatx4 a = accS[ch2 * 4 + t];
                float e0 = ((mw >> (sbase + 0)) & 1u) ? exp2f(a[0] * SCALE_LOG2E) : 0.f;
                float e1 = ((mw >> (sbase + 1)) & 1u) ? exp2f(a[1] * SCALE_LOG2E) : 0.f;
                float e2 = ((mw >> (sbase + 2)) & 1u) ? exp2f(a[2] * SCALE_LOG2E) : 0.f;
                float e3 = ((mw >> (sbase + 3)) & 1u) ? exp2f(a[3] * SCALE_LOG2E) : 0.f;
                lsum += (e0 + e1) + (e2 + e3);
                unsigned int w0 = cvtpk(e0, e1);
                unsigned int w1 = cvtpk(e2, e3);
                int off0 = t * 8 + quad * 2;
                int off1 = off0 + 1;
                Pw[l15 * 32 + ((((off0 >> 2) ^ (l15 & 7)) << 2) | (off0 & 3))] = w0;
                Pw[l15 * 32 + ((((off1 >> 2) ^ (l15 & 7)) << 2) | (off1 & 3))] = w1;
            }
            F8 pa[2];
#pragma unroll
            for (int ks = 0; ks < 2; ++ks) {
                int ci = ks * 4 + quad;
                pa[ks] = *(const F8*)((const unsigned short*)(Pw + l15 * 32) +
                                      ((ci ^ (l15 & 7)) << 3));
            }
#pragma unroll
            for (int dt = 0; dt < 4; ++dt) {
                int d = dt * 16 + l15;
#pragma unroll
                for (int ks = 0; ks < 2; ++ks) {
                    int scl = ch2 * 8 + ks * 4 + quad;
                    int chunk = d * 16 + (scl & 8) + ((scl ^ d) & 7);
                    const F8 bv = *(const F8*)(Vsb + ((size_t)chunk << 3));
                    accO[dt] = __builtin_amdgcn_mfma_f32_16x16x32_bf16(pa[ks].s, bv.s, accO[dt], 0, 0, 0);
                }
            }
        }
        __syncthreads();
    }

    lsum += __shfl_xor(lsum, 16);
    lsum += __shfl_xor(lsum, 32);
    float inv = 1.0f / lsum;

    unsigned short* Ow = Ps + wid * 1024;
#pragma unroll
    for (int r = 0; r < 4; ++r) {
        float invr = __shfl(inv, quad * 4 + r);
        unsigned int p01 = cvtpk(accO[0][r] * invr, accO[1][r] * invr);
        unsigned int p23 = cvtpk(accO[2][r] * invr, accO[3][r] * invr);
        int rowb = (quad * 4 + r) * 64;
        Ow[rowb +  0 + l15] = (unsigned short)p01;
        Ow[rowb + 16 + l15] = (unsigned short)(p01 >> 16);
        Ow[rowb + 32 + l15] = (unsigned short)p23;
        Ow[rowb + 48 + l15] = (unsigned short)(p23 >> 16);
    }
#pragma unroll
    for (int i = 0; i < 2; ++i) {
        int ch = i * 64 + lane;
        int qlocal = ch >> 3, j = ch & 7;
        int qq = qt * 64 + wid * 16 + qlocal;
        int mrow = b * SS + qq;
        int mt = mrow >> 7, rr = mrow & 127;
        int kt2 = h * 2 + (j >> 2), c = j & 3;
        size_t gid = (((size_t)(mt * 32 + kt2) * 4 + c) * 128 + rr);
        *(uint4*)(attn_sw + gid * 8) = *(const uint4*)(Ow + qlocal * 64 + j * 8);
    }
    #undef STAGE
}

// ---------------------------------------------------------------------------
extern "C" void kernel_launch(void* const* d_in, const int* in_sizes, int n_in,
                              void* d_out, int out_size, void* d_ws, size_t ws_size,
                              hipStream_t stream)
{
    const float* x     = (const float*)d_in[0];
    const float* w_qkv = (const float*)d_in[1];
    const float* b_qkv = (const float*)d_in[2];
    const float* w_out = (const float*)d_in[3];
    const float* b_out = (const float*)d_in[4];
    const int* routes  = (const int*)d_in[5];

    char* w = (char*)d_ws;
    unsigned short* xb_sw  = (unsigned short*)(w);                 // 4 MB
    unsigned short* wb1_sw = (unsigned short*)(w + (4u  << 20));   // 6 MB
    unsigned short* wb2_sw = (unsigned short*)(w + (10u << 20));   // 2 MB
    unsigned short* qbuf   = (unsigned short*)(w + (12u << 20));   // 4 MB
    unsigned short* K2g    = (unsigned short*)(w + (24u << 20));   // 4 MB
    unsigned short* Vtg    = (unsigned short*)(w + (28u << 20));   // 4 MB
    unsigned short* attnsw = (unsigned short*)(w + (32u << 20));   // 4 MB
    unsigned int*   maskg  = (unsigned int*)(w + (36u << 20));     // 32 KB

    prep_kernel<<<3074, 256, 0, stream>>>(x, w_qkv, w_out, routes,
                                          xb_sw, wb1_sw, wb2_sw, maskg);

    gemm_qkv_fused<<<768, 256, 0, stream>>>(xb_sw, wb1_sw, b_qkv,
                                            qbuf, K2g, Vtg);

    attn_kernel<<<512, 256, 0, stream>>>(qbuf, K2g, Vtg, maskg, attnsw);

    gemm_out<<<512, 256, 0, stream>>>(attnsw, wb2_sw, b_out, (float*)d_out);
}

// Round 11
// 137.557 us; speedup vs baseline: 1.0468x; 1.0318x over previous
//
#include <hip/hip_runtime.h>
#include <hip/hip_bf16.h>

#define BB 4
#define SS 512
#define DD 1024
#define HH 16
#define KR 64
#define HDIM 64
#define THREE_D 3072
#define M_ROWS 2048
#define SCALE_F 0.125f
#define SCALE_LOG2E 0.1803368801111144f

typedef __attribute__((ext_vector_type(8))) short short8;
typedef __attribute__((ext_vector_type(4))) float floatx4;

union F8 { short8 s; unsigned int u[4]; unsigned short h[8]; };

__device__ inline float bfu(unsigned short h){ union{unsigned int u; float f;} c; c.u = ((unsigned int)h) << 16; return c.f; }
__device__ inline unsigned short f2bf(float f){
    union{float f; unsigned int u;} c; c.f = f;
    unsigned int u = c.u;
    return (unsigned short)((u + 0x7fffu + ((u >> 16) & 1u)) >> 16);   // RNE
}
// packed RNE f32x2 -> bf16x2 in one instruction (bit-identical to f2bf for
// finite inputs; no NaNs on these paths). lo in [15:0], hi in [31:16].
__device__ inline unsigned int cvtpk(float lo, float hi){
    unsigned int d;
    asm("v_cvt_pk_bf16_f32 %0, %1, %2" : "=v"(d) : "v"(lo), "v"(hi));
    return d;
}

#define GLOAD_LDS16(g, l)                                                     \
    __builtin_amdgcn_global_load_lds(                                         \
        (const __attribute__((address_space(1))) unsigned int*)(g),           \
        (__attribute__((address_space(3))) unsigned int*)(l), 16, 0, 0)

// ---------------------------------------------------------------------------
// prep: fused cvtA (x->swizzled bf16) + cvtB(w_qkv) + cvtB(w_out) + mask
// ---------------------------------------------------------------------------
__global__ __launch_bounds__(256) void prep_kernel(
    const float* __restrict__ x, const float* __restrict__ w_qkv,
    const float* __restrict__ w_out, const int* __restrict__ routes,
    unsigned short* __restrict__ xb_sw, unsigned short* __restrict__ wb1_sw,
    unsigned short* __restrict__ wb2_sw, unsigned int* __restrict__ maskg)
{
    const int bx = blockIdx.x;
    const int tid = threadIdx.x;
    if (bx < 1024) {
        int gid = bx * 256 + tid;
        int r  = gid & 127;
        int c  = (gid >> 7) & 3;
        int kt = (gid >> 9) & 31;
        int mt = gid >> 14;
        const float* src = x + ((size_t)(mt * 128 + r)) * 1024 + kt * 32 + c * 8;
        float4 a = *(const float4*)src;
        float4 b = *(const float4*)(src + 4);
        F8 o;
        o.u[0] = cvtpk(a.x, a.y);
        o.u[1] = cvtpk(a.z, a.w);
        o.u[2] = cvtpk(b.x, b.y);
        o.u[3] = cvtpk(b.z, b.w);
        *(uint4*)(xb_sw + (size_t)gid * 8) = *(uint4*)&o;
    } else if (bx < 3072) {
        const float* w;
        unsigned short* out;
        int gid, N;
        if (bx < 2560) { w = w_qkv; out = wb1_sw; N = THREE_D; gid = (bx - 1024) * 256 + tid; }
        else           { w = w_out; out = wb2_sw; N = DD;      gid = (bx - 2560) * 256 + tid; }
        int r  = gid & 127;
        int c  = (gid >> 7) & 3;
        int kt = (gid >> 9) & 31;
        int nt = gid >> 14;
        int n = nt * 128 + r;
        int kbase = kt * 32 + c * 8;
        float v[8];
#pragma unroll
        for (int j = 0; j < 8; ++j)
            v[j] = w[(size_t)(kbase + j) * N + n];
        F8 o;
#pragma unroll
        for (int j = 0; j < 4; ++j)
            o.u[j] = cvtpk(v[2 * j], v[2 * j + 1]);
        *(uint4*)(out + (size_t)gid * 8) = *(uint4*)&o;
    } else {
        int q = (bx - 3072) * 256 + tid;
        unsigned int w[16];
#pragma unroll
        for (int i = 0; i < 16; ++i) w[i] = 0u;
        for (int j = 0; j < KR; ++j) {
            int r = routes[q * KR + j];
            if (r <= q) w[r >> 5] |= 1u << (r & 31);
        }
#pragma unroll
        for (int sw = 0; sw < 16; ++sw) maskg[sw * SS + q] = w[sw];
    }
}

// ---------------------------------------------------------------------------
// GEMM1 (QKV) + FUSED BLEND: 64x128 tile, BK=128, 768 blocks, 256 threads.
// (R8 form exact — proven best at 138.0us.)
// ---------------------------------------------------------------------------
__global__ __launch_bounds__(256, 3) void gemm_qkv_fused(
    const unsigned short* __restrict__ Asw,
    const unsigned short* __restrict__ Bsw,
    const float* __restrict__ bias,
    unsigned short* __restrict__ qb,
    unsigned short* __restrict__ K2g,
    unsigned short* __restrict__ Vtg)
{
    __shared__ __align__(16) unsigned short Sh[26624];   // 52 KB
    unsigned short* Blds = Sh + 10240;                   // B: 4 kh x 4096

    const int tid  = threadIdx.x;
    const int lane = tid & 63;
    const int wid  = tid >> 6;
    const int l15  = lane & 15;
    const int quad = lane >> 4;

    const int bid  = blockIdx.x;
    const int xcd  = bid & 7;
    const int loc  = bid >> 3;
    const int mt64 = (xcd & 3) * 8 + (loc & 7);
    const int nt   = (xcd >> 2) * 12 + (loc >> 3);

    const bool isQ = (nt < 8);
    const int m0   = mt64 * 64;
    const int n0   = nt * 128;
    const int wn   = wid * 32;
    const int base_m = isQ ? m0 : (m0 - 8);

    int rA = base_m + lane;        rA = rA < 0 ? 0 : (rA > 2047 ? 2047 : rA);
    int rB = base_m + 64 + l15;    rB = rB < 0 ? 0 : (rB > 2047 ? 2047 : rB);
    const int cB = lane >> 4;
    const size_t aOffA = ((size_t)(rA >> 7) * 128) * 1024 + (size_t)(rA & 127) * 8;
    const size_t aOffB = ((size_t)(rB >> 7) * 128) * 1024 + (size_t)(rB & 127) * 8;

    floatx4 acc[5][2];
#pragma unroll
    for (int i = 0; i < 5; ++i)
#pragma unroll
        for (int j = 0; j < 2; ++j) acc[i][j] = (floatx4){0.f, 0.f, 0.f, 0.f};

    for (int kt8 = 0; kt8 < 8; ++kt8) {
#pragma unroll
        for (int kh = 0; kh < 4; ++kh) {
            int kt = kt8 * 4 + kh;
            const unsigned short* ga = Asw + aOffA + (size_t)(kt * 4 + wid) * 1024;
            GLOAD_LDS16(ga, Sh + kh * 2560 + wid * 512 + lane * 8);
            if (!isQ && wid == 0) {
                const unsigned short* ga2 = Asw + aOffB + (size_t)(kt * 4 + cB) * 1024;
                GLOAD_LDS16(ga2, Sh + kh * 2560 + 2048 + lane * 8);
            }
            const unsigned short* gb = Bsw + (size_t)(nt * 32 + kt) * 4096 + wid * 1024 + lane * 8;
            GLOAD_LDS16(gb,       Blds + kh * 4096 + wid * 1024 + lane * 8);
            GLOAD_LDS16(gb + 512, Blds + kh * 4096 + wid * 1024 + 512 + lane * 8);
        }
        __syncthreads();

#pragma unroll
        for (int kh = 0; kh < 4; ++kh) {
            F8 af[5], bf[2];
#pragma unroll
            for (int emi = 0; emi < 4; ++emi)
                af[emi] = *(const F8*)(Sh + kh * 2560 + (size_t)(quad * 64 + emi * 16 + l15) * 8);
            if (!isQ)
                af[4] = *(const F8*)(Sh + kh * 2560 + 2048 + (size_t)(quad * 16 + l15) * 8);
#pragma unroll
            for (int ni = 0; ni < 2; ++ni)
                bf[ni] = *(const F8*)(Blds + kh * 4096 + (size_t)(quad * 128 + wn + ni * 16 + l15) * 8);
#pragma unroll
            for (int emi = 0; emi < 5; ++emi) {
                if (emi == 4 && isQ) continue;
#pragma unroll
                for (int ni = 0; ni < 2; ++ni)
                    acc[emi][ni] = __builtin_amdgcn_mfma_f32_16x16x32_bf16(
                        af[emi].s, bf[ni].s, acc[emi][ni], 0, 0, 0);
            }
        }
        __syncthreads();
    }

    if (isQ) {
        // ---------- Q path: original epilogue, rows -> qbuf ----------
#pragma unroll
        for (int mi = 0; mi < 4; ++mi) {
#pragma unroll
            for (int ni = 0; ni < 2; ++ni) {
                int col = wn + ni * 16 + l15;
                float bv = bias[n0 + col];
                int row0 = mi * 16 + quad * 4;
                unsigned int p01 = cvtpk(acc[mi][ni][0] + bv, acc[mi][ni][1] + bv);
                unsigned int p23 = cvtpk(acc[mi][ni][2] + bv, acc[mi][ni][3] + bv);
                Sh[(row0 + 0) * 136 + col] = (unsigned short)p01;
                Sh[(row0 + 1) * 136 + col] = (unsigned short)(p01 >> 16);
                Sh[(row0 + 2) * 136 + col] = (unsigned short)p23;
                Sh[(row0 + 3) * 136 + col] = (unsigned short)(p23 >> 16);
            }
        }
        __syncthreads();
        for (int i = tid; i < 1024; i += 256) {
            int rr = i >> 4, cc = i & 15;
            int grow = m0 + rr, gcol = n0 + cc * 8;
            int b = grow >> 9, s = grow & 511;
            int h = gcol >> 6, hd = gcol & 63;
            uint4 val = *(const uint4*)(Sh + rr * 136 + cc * 8);
            *(uint4*)(qb + (((size_t)(b * HH + h) * SS) + s) * HDIM + hd) = val;
        }
    } else {
        // ---------- K/V path: in-register s-blend then layout write ----------
        const bool firstBlk = ((mt64 & 7) == 0);
        const bool lastBlk  = ((mt64 & 7) == 7);
#pragma unroll
        for (int ni = 0; ni < 2; ++ni) {
            int col = wn + ni * 16 + l15;
            float bv = bias[n0 + col];
#pragma unroll
            for (int emi = 0; emi < 5; ++emi) {
                float c0 = acc[emi][ni][0];
                float c3 = acc[emi][ni][3];
                float lA = __shfl_up(c3, 16);
                float lB = (emi > 0) ? __shfl(acc[emi - 1][ni][3], l15 + 48) : 0.f;
                float left0 = (quad == 0) ? lB : lA;
                float rA_ = __shfl_down(c0, 16);
                float rB_ = (emi < 4) ? __shfl(acc[emi + 1][ni][0], l15) : 0.f;
                float right3 = (quad == 3) ? rB_ : rA_;
                float bl[4];
#pragma unroll
                for (int r = 0; r < 4; ++r) {
                    float c = acc[emi][ni][r];
                    float lv = (r == 0) ? left0 : acc[emi][ni][r - 1];
                    float rv = (r == 3) ? right3 : acc[emi][ni][r + 1];
                    if (firstBlk && emi == 0 && quad == 2 && r == 0) lv = c;
                    if (lastBlk  && emi == 4 && quad == 1 && r == 3) rv = c;
                    bl[r] = 0.75f * c + 0.125f * (lv + rv) + bv;
                }
                unsigned int p01 = cvtpk(bl[0], bl[1]);
                unsigned int p23 = cvtpk(bl[2], bl[3]);
                int t0 = emi * 16 + quad * 4 - 8;
                if (t0 >= 0     && t0 < 64)     Sh[t0 * 136 + col]       = (unsigned short)p01;
                if (t0 + 1 >= 0 && t0 + 1 < 64) Sh[(t0 + 1) * 136 + col] = (unsigned short)(p01 >> 16);
                if (t0 + 2 >= 0 && t0 + 2 < 64) Sh[(t0 + 2) * 136 + col] = (unsigned short)p23;
                if (t0 + 3 >= 0 && t0 + 3 < 64) Sh[(t0 + 3) * 136 + col] = (unsigned short)(p23 >> 16);
            }
        }
        __syncthreads();

        const int b   = m0 >> 9;
        const int qd  = (m0 >> 7) & 3;
        const int s0q = m0 & 127;
        if (nt < 16) {
            for (int i = tid; i < 1024; i += 256) {
                int hl = i >> 9, t = (i >> 3) & 63, cc = i & 7;
                int bh = b * 16 + (nt - 8) * 2 + hl;
                int sl = s0q + t;
                uint4 val = *(const uint4*)(Sh + t * 136 + hl * 64 + cc * 8);
                *(uint4*)(K2g + ((size_t)(bh * 4 + qd)) * 8192 +
                          (size_t)(sl * 8 + (cc ^ (sl & 7))) * 8) = val;
            }
        } else {
            for (int i = tid; i < 1024; i += 256) {
                int hl = i >> 9, d = (i >> 3) & 63, t8 = i & 7;
                int bh = b * 16 + (nt - 16) * 2 + hl;
                int scl = (s0q >> 3) + t8;
                F8 o;
#pragma unroll
                for (int a = 0; a < 8; ++a)
                    o.h[a] = Sh[(t8 * 8 + a) * 136 + hl * 64 + d];
                int chunk = d * 16 + (scl & 8) + ((scl ^ d) & 7);
                *(uint4*)(Vtg + ((size_t)(bh * 4 + qd)) * 8192 + (size_t)chunk * 8) = *(uint4*)&o;
            }
        }
    }
}

// ---------------------------------------------------------------------------
// GEMM2 (out proj): 64x64 tile, BK=128 single-buffered (R1 form).
// ---------------------------------------------------------------------------
__global__ __launch_bounds__(256) void gemm_out(
    const unsigned short* __restrict__ Asw,
    const unsigned short* __restrict__ Bsw,
    const float* __restrict__ bias,
    float* __restrict__ Cout)
{
    __shared__ __align__(16) unsigned short Alds[8192];
    __shared__ __align__(16) unsigned short Blds[8192];

    const int tid  = threadIdx.x;
    const int lane = tid & 63;
    const int wid  = tid >> 6;
    const int l15  = lane & 15;
    const int quad = lane >> 4;

    const int bid  = blockIdx.x;
    const int xcd  = bid & 7;
    const int loc  = bid >> 3;
    const int mt64 = (xcd & 3) * 8 + (loc & 7);
    const int nt64 = (xcd >> 2) * 8 + (loc >> 3);

    const int mt  = mt64 >> 1;
    const int rh  = (mt64 & 1) * 64;
    const int ntB = nt64 >> 1;
    const int rhB = (nt64 & 1) * 64;
    const int wm  = (wid >> 1) * 32;
    const int wn  = (wid & 1) * 32;

    floatx4 acc[2][2];
#pragma unroll
    for (int i = 0; i < 2; ++i)
#pragma unroll
        for (int j = 0; j < 2; ++j) acc[i][j] = (floatx4){0.f, 0.f, 0.f, 0.f};

    for (int kt4 = 0; kt4 < 8; ++kt4) {
#pragma unroll
        for (int kh = 0; kh < 4; ++kh) {
            int kt = kt4 * 4 + kh;
            const unsigned short* ga = Asw + ((size_t)(mt  * 32 + kt) * 4 + wid) * 1024 + (rh  + lane) * 8;
            const unsigned short* gb = Bsw + ((size_t)(ntB * 32 + kt) * 4 + wid) * 1024 + (rhB + lane) * 8;
            GLOAD_LDS16(ga, Alds + kh * 2048 + wid * 512 + lane * 8);
            GLOAD_LDS16(gb, Blds + kh * 2048 + wid * 512 + lane * 8);
        }
        __syncthreads();

#pragma unroll
        for (int kh = 0; kh < 4; ++kh) {
            F8 af[2], bf[2];
#pragma unroll
            for (int mi = 0; mi < 2; ++mi)
                af[mi] = *(const F8*)(Alds + kh * 2048 + (size_t)(quad * 64 + wm + mi * 16 + l15) * 8);
#pragma unroll
            for (int ni = 0; ni < 2; ++ni)
                bf[ni] = *(const F8*)(Blds + kh * 2048 + (size_t)(quad * 64 + wn + ni * 16 + l15) * 8);
#pragma unroll
            for (int mi = 0; mi < 2; ++mi)
#pragma unroll
                for (int ni = 0; ni < 2; ++ni)
                    acc[mi][ni] = __builtin_amdgcn_mfma_f32_16x16x32_bf16(
                        af[mi].s, bf[ni].s, acc[mi][ni], 0, 0, 0);
        }
        __syncthreads();
    }

    const int m0 = mt64 * 64;
    const int n0 = nt64 * 64;
#pragma unroll
    for (int mi = 0; mi < 2; ++mi) {
#pragma unroll
        for (int ni = 0; ni < 2; ++ni) {
            int col = n0 + wn + ni * 16 + l15;
            float bv = bias[col];
#pragma unroll
            for (int r = 0; r < 4; ++r) {
                int row = m0 + wm + mi * 16 + quad * 4 + r;
                Cout[(size_t)row * DD + col] = acc[mi][ni][r] + bv;
            }
        }
    }
}

// ---------------------------------------------------------------------------
// Dense masked flash attention with CAUSAL CHUNK SKIPPING. (R8 form exact —
// 64-chunk-granular skip; proven best at 138.0us. R10's 16-tile skip +
// zero-init was +3.9us vs R8 — reverted.)
// ---------------------------------------------------------------------------
__global__ __launch_bounds__(256) void attn_kernel(
    const unsigned short* __restrict__ qb,
    const unsigned short* __restrict__ K2g,
    const unsigned short* __restrict__ Vtg,
    const unsigned int* __restrict__ maskg,
    unsigned short* __restrict__ attn_sw)
{
    __shared__ __align__(16) unsigned short Ks2[2][8192];  // 32 KB
    __shared__ __align__(16) unsigned short Vs2[2][8192];  // 32 KB
    __shared__ __align__(16) unsigned short Ps[4096];      // 8 KB

    const int bid = blockIdx.x;
    const int xcd = bid & 7;
    const int loc = bid >> 3;
    const int bh  = xcd * 8 + (loc & 7);
    const int qt8 = loc >> 3;
    const int qt  = (qt8 < 4) ? qt8 : 11 - qt8;   // {0,1,2,3,7,6,5,4} pairing
    const int b = bh >> 4, h = bh & 15;
    const int tid  = threadIdx.x;
    const int lane = tid & 63;
    const int wid  = tid >> 6;
    const int l15  = lane & 15;
    const int quad = lane >> 4;

    const int nq    = (qt >> 1) + 1;
    const int qmaxw = qt * 64 + wid * 16 + 15;

    const unsigned short* Kbh = K2g + (size_t)bh * 4 * 8192;
    const unsigned short* Vbh = Vtg + (size_t)bh * 4 * 8192;

    #define STAGE(qd, bufi) do {                                              \
        const unsigned short* kq = Kbh + (size_t)(qd) * 8192 + wid * 2048;    \
        const unsigned short* vq = Vbh + (size_t)(qd) * 8192 + wid * 2048;    \
        unsigned short* kl = Ks2[bufi] + wid * 2048;                          \
        unsigned short* vl = Vs2[bufi] + wid * 2048;                          \
        GLOAD_LDS16(kq + lane * 8,        kl + lane * 8);                     \
        GLOAD_LDS16(kq + 512 + lane * 8,  kl + 512 + lane * 8);               \
        GLOAD_LDS16(kq + 1024 + lane * 8, kl + 1024 + lane * 8);              \
        GLOAD_LDS16(kq + 1536 + lane * 8, kl + 1536 + lane * 8);              \
        GLOAD_LDS16(vq + lane * 8,        vl + lane * 8);                     \
        GLOAD_LDS16(vq + 512 + lane * 8,  vl + 512 + lane * 8);               \
        GLOAD_LDS16(vq + 1024 + lane * 8, vl + 1024 + lane * 8);              \
        GLOAD_LDS16(vq + 1536 + lane * 8, vl + 1536 + lane * 8);              \
    } while (0)

    const int q = qt * 64 + wid * 16 + l15;

    F8 qf[2];
    {
        const unsigned short* qrow = qb + ((size_t)bh * SS + q) * 64;
        qf[0] = *(const F8*)(qrow + quad * 8);
        qf[1] = *(const F8*)(qrow + 32 + quad * 8);
    }

    STAGE(0, 0);
    __syncthreads();

    floatx4 accO[4];
#pragma unroll
    for (int dt = 0; dt < 4; ++dt) accO[dt] = (floatx4){0.f, 0.f, 0.f, 0.f};
    float lsum = 0.f;
    unsigned int* Pw = (unsigned int*)Ps + wid * 512;

    for (int qd = 0; qd < nq; ++qd) {
        if (qd + 1 < nq) STAGE(qd + 1, (qd + 1) & 1);
        const unsigned short* Ksb = Ks2[qd & 1];
        const unsigned short* Vsb = Vs2[qd & 1];
        const int sbase128 = qd * 128;

        floatx4 accS[8];
#pragma unroll
        for (int st = 0; st < 8; ++st) {
            if (sbase128 + (st >> 2) * 64 <= qmaxw) {
                int srow = st * 16 + l15;
                const F8 k0 = *(const F8*)(Ksb + (((srow << 3) | ( quad      ^ (srow & 7))) << 3));
                const F8 k1 = *(const F8*)(Ksb + (((srow << 3) | ((4 + quad) ^ (srow & 7))) << 3));
                floatx4 a = (floatx4){0.f, 0.f, 0.f, 0.f};
                a = __builtin_amdgcn_mfma_f32_16x16x32_bf16(k0.s, qf[0].s, a, 0, 0, 0);
                a = __builtin_amdgcn_mfma_f32_16x16x32_bf16(k1.s, qf[1].s, a, 0, 0, 0);
                accS[st] = a;
            }
        }

#pragma unroll
        for (int ch2 = 0; ch2 < 2; ++ch2) {
            if (sbase128 + ch2 * 64 > qmaxw) continue;
            unsigned int mw0 = maskg[(qd * 4 + ch2 * 2) * SS + q];
            unsigned int mw1 = maskg[(qd * 4 + ch2 * 2 + 1) * SS + q];
#pragma unroll
            for (int t = 0; t < 4; ++t) {
                unsigned int mw = (t & 2) ? mw1 : mw0;
                int sbase = (t & 1) * 16 + quad * 4;
                floatx4 a = accS[ch2 * 4 + t];
                float e0 = ((mw >> (sbase + 0)) & 1u) ? exp2f(a[0] * SCALE_LOG2E) : 0.f;
                float e1 = ((mw >> (sbase + 1)) & 1u) ? exp2f(a[1] * SCALE_LOG2E) : 0.f;
                float e2 = ((mw >> (sbase + 2)) & 1u) ? exp2f(a[2] * SCALE_LOG2E) : 0.f;
                float e3 = ((mw >> (sbase + 3)) & 1u) ? exp2f(a[3] * SCALE_LOG2E) : 0.f;
                lsum += (e0 + e1) + (e2 + e3);
                unsigned int w0 = cvtpk(e0, e1);
                unsigned int w1 = cvtpk(e2, e3);
                int off0 = t * 8 + quad * 2;
                int off1 = off0 + 1;
                Pw[l15 * 32 + ((((off0 >> 2) ^ (l15 & 7)) << 2) | (off0 & 3))] = w0;
                Pw[l15 * 32 + ((((off1 >> 2) ^ (l15 & 7)) << 2) | (off1 & 3))] = w1;
            }
            F8 pa[2];
#pragma unroll
            for (int ks = 0; ks < 2; ++ks) {
                int ci = ks * 4 + quad;
                pa[ks] = *(const F8*)((const unsigned short*)(Pw + l15 * 32) +
                                      ((ci ^ (l15 & 7)) << 3));
            }
#pragma unroll
            for (int dt = 0; dt < 4; ++dt) {
                int d = dt * 16 + l15;
#pragma unroll
                for (int ks = 0; ks < 2; ++ks) {
                    int scl = ch2 * 8 + ks * 4 + quad;
                    int chunk = d * 16 + (scl & 8) + ((scl ^ d) & 7);
                    const F8 bv = *(const F8*)(Vsb + ((size_t)chunk << 3));
                    accO[dt] = __builtin_amdgcn_mfma_f32_16x16x32_bf16(pa[ks].s, bv.s, accO[dt], 0, 0, 0);
                }
            }
        }
        __syncthreads();
    }

    lsum += __shfl_xor(lsum, 16);
    lsum += __shfl_xor(lsum, 32);
    float inv = 1.0f / lsum;

    unsigned short* Ow = Ps + wid * 1024;
#pragma unroll
    for (int r = 0; r < 4; ++r) {
        float invr = __shfl(inv, quad * 4 + r);
        unsigned int p01 = cvtpk(accO[0][r] * invr, accO[1][r] * invr);
        unsigned int p23 = cvtpk(accO[2][r] * invr, accO[3][r] * invr);
        int rowb = (quad * 4 + r) * 64;
        Ow[rowb +  0 + l15] = (unsigned short)p01;
        Ow[rowb + 16 + l15] = (unsigned short)(p01 >> 16);
        Ow[rowb + 32 + l15] = (unsigned short)p23;
        Ow[rowb + 48 + l15] = (unsigned short)(p23 >> 16);
    }
#pragma unroll
    for (int i = 0; i < 2; ++i) {
        int ch = i * 64 + lane;
        int qlocal = ch >> 3, j = ch & 7;
        int qq = qt * 64 + wid * 16 + qlocal;
        int mrow = b * SS + qq;
        int mt = mrow >> 7, rr = mrow & 127;
        int kt2 = h * 2 + (j >> 2), c = j & 3;
        size_t gid = (((size_t)(mt * 32 + kt2) * 4 + c) * 128 + rr);
        *(uint4*)(attn_sw + gid * 8) = *(const uint4*)(Ow + qlocal * 64 + j * 8);
    }
    #undef STAGE
}

// ---------------------------------------------------------------------------
extern "C" void kernel_launch(void* const* d_in, const int* in_sizes, int n_in,
                              void* d_out, int out_size, void* d_ws, size_t ws_size,
                              hipStream_t stream)
{
    const float* x     = (const float*)d_in[0];
    const float* w_qkv = (const float*)d_in[1];
    const float* b_qkv = (const float*)d_in[2];
    const float* w_out = (const float*)d_in[3];
    const float* b_out = (const float*)d_in[4];
    const int* routes  = (const int*)d_in[5];

    char* w = (char*)d_ws;
    unsigned short* xb_sw  = (unsigned short*)(w);                 // 4 MB
    unsigned short* wb1_sw = (unsigned short*)(w + (4u  << 20));   // 6 MB
    unsigned short* wb2_sw = (unsigned short*)(w + (10u << 20));   // 2 MB
    unsigned short* qbuf   = (unsigned short*)(w + (12u << 20));   // 4 MB
    unsigned short* K2g    = (unsigned short*)(w + (24u << 20));   // 4 MB
    unsigned short* Vtg    = (unsigned short*)(w + (28u << 20));   // 4 MB
    unsigned short* attnsw = (unsigned short*)(w + (32u << 20));   // 4 MB
    unsigned int*   maskg  = (unsigned int*)(w + (36u << 20));     // 32 KB

    prep_kernel<<<3074, 256, 0, stream>>>(x, w_qkv, w_out, routes,
                                          xb_sw, wb1_sw, wb2_sw, maskg);

    gemm_qkv_fused<<<768, 256, 0, stream>>>(xb_sw, wb1_sw, b_qkv,
                                            qbuf, K2g, Vtg);

    attn_kernel<<<512, 256, 0, stream>>>(qbuf, K2g, Vtg, maskg, attnsw);

    gemm_out<<<512, 256, 0, stream>>>(attnsw, wb2_sw, b_out, (float*)d_out);
}